// Round 4
// baseline (347.749 us; speedup 1.0000x reference)
//
#include <hip/hip_runtime.h>
#include <hip/hip_bf16.h>

#define NT 8192
#define DIM 512
#define NE 16

#define BM 256
#define BN 256
#define BK 64
#define NKT 8   // DIM / BK

typedef __attribute__((ext_vector_type(4))) float f32x4;
typedef __attribute__((ext_vector_type(8))) short short8;

typedef __attribute__((address_space(3))) void lds_void_t;
typedef const __attribute__((address_space(1))) void g_void_t;

__device__ inline unsigned short f2b(float f) {
  union { __hip_bfloat16 b; unsigned short u; } cv;
  cv.b = __float2bfloat16(f);  // RNE
  return cv.u;
}

// Convert x [NT*DIM] and W [NE*DIM*DIM] fp32 -> bf16 into workspace.
__global__ __launch_bounds__(256) void cvt_kernel(const float* __restrict__ x,
                                                  const float* __restrict__ W,
                                                  unsigned short* __restrict__ xb,
                                                  unsigned short* __restrict__ wb) {
  long t = (long)blockIdx.x * 256 + threadIdx.x;
  long i = t * 8;
  const float* src;
  unsigned short* dst;
  if (i < (long)NT * DIM) {
    src = x + i;
    dst = xb + i;
  } else {
    long j = i - (long)NT * DIM;
    src = W + j;
    dst = wb + j;
  }
  float4 v0 = reinterpret_cast<const float4*>(src)[0];
  float4 v1 = reinterpret_cast<const float4*>(src)[1];
  short8 o;
  o[0] = (short)f2b(v0.x); o[1] = (short)f2b(v0.y);
  o[2] = (short)f2b(v0.z); o[3] = (short)f2b(v0.w);
  o[4] = (short)f2b(v1.x); o[5] = (short)f2b(v1.y);
  o[6] = (short)f2b(v1.z); o[7] = (short)f2b(v1.w);
  *reinterpret_cast<short8*>(dst) = o;
}

#define GLOAD(gp, lp) __builtin_amdgcn_global_load_lds((g_void_t*)(gp), (lds_void_t*)(lp), 16, 0, 0)

// C[e] = x @ W[e]^T + b[e].
// 256x256 tile, BK=64, 8 waves (2M x 4N), double-buffered LDS (128 KiB),
// counted vmcnt(8) pipeline, XOR-swizzled LDS (chunk ^= row&7, pre-swizzled
// global source so global_load_lds dest stays linear), setprio around MFMA.
__global__ __launch_bounds__(512, 2) void expert_gemm(const unsigned short* __restrict__ xb,
                                                      const unsigned short* __restrict__ wb,
                                                      const float* __restrict__ bias,
                                                      float* __restrict__ out) {
  extern __shared__ char smem[];  // 2 * (32KB A + 32KB B) = 131072 B

  const int tid  = threadIdx.x;
  const int lane = tid & 63;
  const int w    = tid >> 6;     // 0..7
  const int wr   = w >> 2;       // 0..1  (128-row band)
  const int wc   = w & 3;        // 0..3  (64-col band)

  const int bid = blockIdx.x;    // e(16) * tn(2) * tm(32)
  const int e   = bid >> 6;
  const int tn  = (bid >> 5) & 1;
  const int tm  = bid & 31;

  const int m0 = tm * BM;
  const int n0 = tn * BN;

  const unsigned short* Ag = xb + (size_t)m0 * DIM;
  const unsigned short* Bg = wb + (size_t)e * DIM * DIM + (size_t)n0 * DIM;

  // ---- staging geometry (per lane) ----
  // instr j of wave w writes LDS bytes [(w*4+j)*1024, +1024); lane l writes +l*16.
  // Linear LDS layout: [256 rows][64 cols bf16] -> row = byteoff>>7, pos = (byteoff>>4)&7.
  // Swizzle: LDS pos p of row r holds source chunk (p ^ (r&7)).
  const int slrow = lane >> 3;                     // row-within-8 for this lane
  const int scol  = ((lane & 7) ^ slrow) * 8;      // pre-swizzled source column (elems)

  // ---- fragment read geometry ----
  const int q  = lane >> 4;      // 0..3 -> k offset q*8
  const int fr = lane & 15;      // fragment row/col
  const int axor = fr & 7;       // row&7 for all frag rows (row ≡ fr mod 8)
  const int cx0 = ((0 * 4 + q) ^ axor) << 4;       // kk=0 swizzled byte offset of chunk
  const int cx1 = ((1 * 4 + q) ^ axor) << 4;       // kk=1

  f32x4 acc[8][4] = {};   // [mi 0..7][ni 0..3] -> wave's 128x64 output
  short8 a[4][2];         // A frags for current mh (4 mi x 2 kk)
  short8 b[2][2];         // B frags for current (nh): 2 ni x 2 kk

  // ---- prologue: stage tile 0 into buf0, drain, barrier ----
  {
    char* lA = smem;
    char* lB = smem + 32768;
#pragma unroll
    for (int j = 0; j < 4; ++j) {
      const int grow = (w * 4 + j) * 8 + slrow;
      GLOAD(Ag + (size_t)grow * DIM + scol, lA + (w * 4 + j) * 1024);
      GLOAD(Bg + (size_t)grow * DIM + scol, lB + (w * 4 + j) * 1024);
    }
  }
  asm volatile("s_waitcnt vmcnt(0)" ::: "memory");
  __builtin_amdgcn_s_barrier();
  asm volatile("" ::: "memory");

  for (int kt = 0; kt < NKT; ++kt) {
    const int cur = kt & 1;
    // stage next tile into the other buffer (its previous contents were last
    // read in tile kt-1; end-of-tile barrier already passed)
    if (kt + 1 < NKT) {
      char* lA = smem + (cur ^ 1) * 65536;
      char* lB = lA + 32768;
      const int kc = (kt + 1) * BK + scol;
#pragma unroll
      for (int j = 0; j < 4; ++j) {
        const int grow = (w * 4 + j) * 8 + slrow;
        GLOAD(Ag + (size_t)grow * DIM + kc, lA + (w * 4 + j) * 1024);
        GLOAD(Bg + (size_t)grow * DIM + kc, lB + (w * 4 + j) * 1024);
      }
      asm volatile("s_waitcnt vmcnt(8)" ::: "memory");  // tile kt fully landed
    } else {
      asm volatile("s_waitcnt vmcnt(0)" ::: "memory");  // tail: drain tile 7
    }
    __builtin_amdgcn_s_barrier();   // all waves' tile-kt data visible
    asm volatile("" ::: "memory");

    const char* lA = smem + cur * 65536;
    const char* lB = lA + 32768;

#pragma unroll
    for (int ph = 0; ph < 4; ++ph) {
      const int mh = ph >> 1;   // quadrant: m-half of wave's 128 rows
      const int nh = ph & 1;    // n-half of wave's 64 cols
      if (nh == 0) {
#pragma unroll
        for (int mi = 0; mi < 4; ++mi) {
          const int ra = wr * 128 + mh * 64 + mi * 16 + fr;
          a[mi][0] = *reinterpret_cast<const short8*>(lA + ra * 128 + cx0);
          a[mi][1] = *reinterpret_cast<const short8*>(lA + ra * 128 + cx1);
        }
      }
#pragma unroll
      for (int ni = 0; ni < 2; ++ni) {
        const int rb = wc * 64 + nh * 32 + ni * 16 + fr;
        b[ni][0] = *reinterpret_cast<const short8*>(lB + rb * 128 + cx0);
        b[ni][1] = *reinterpret_cast<const short8*>(lB + rb * 128 + cx1);
      }
      __builtin_amdgcn_s_setprio(1);
#pragma unroll
      for (int kk = 0; kk < 2; ++kk)
#pragma unroll
        for (int mi = 0; mi < 4; ++mi)
#pragma unroll
          for (int ni = 0; ni < 2; ++ni)
            acc[mh * 4 + mi][nh * 2 + ni] = __builtin_amdgcn_mfma_f32_16x16x32_bf16(
                a[mi][kk], b[ni][kk], acc[mh * 4 + mi][nh * 2 + ni], 0, 0, 0);
      __builtin_amdgcn_s_setprio(0);
    }

    asm volatile("" ::: "memory");
    __builtin_amdgcn_s_barrier();   // reads of buf[cur] done before next overwrite
    asm volatile("" ::: "memory");
  }

  // ---- epilogue: C row = q*4 + reg, col = fr (verified mapping); fused bias ----
  float bv[4];
#pragma unroll
  for (int ni = 0; ni < 4; ++ni)
    bv[ni] = bias[e * DIM + n0 + wc * 64 + ni * 16 + fr];

  float* outE = out + (size_t)e * NT * DIM;
#pragma unroll
  for (int mi = 0; mi < 8; ++mi) {
#pragma unroll
    for (int reg = 0; reg < 4; ++reg) {
      const int row = m0 + wr * 128 + mi * 16 + q * 4 + reg;
      float* op = outE + (size_t)row * DIM + n0 + wc * 64 + fr;
#pragma unroll
      for (int ni = 0; ni < 4; ++ni)
        op[ni * 16] = acc[mi][ni][reg] + bv[ni];
    }
  }
}

extern "C" void kernel_launch(void* const* d_in, const int* in_sizes, int n_in,
                              void* d_out, int out_size, void* d_ws, size_t ws_size,
                              hipStream_t stream) {
  const float* x = (const float*)d_in[0];
  const float* W = (const float*)d_in[1];
  const float* b = (const float*)d_in[2];
  float* out = (float*)d_out;

  unsigned short* xb = (unsigned short*)d_ws;                 // 8 MB
  unsigned short* wb = xb + (size_t)NT * DIM;                 // 8 MB

  // (NT*DIM + NE*DIM*DIM) / 8 elems-per-thread / 256 threads = 4096 blocks
  cvt_kernel<<<4096, 256, 0, stream>>>(x, W, xb, wb);

  // allow 128 KiB dynamic LDS (idempotent; host-side, graph-capture-safe)
  (void)hipFuncSetAttribute(reinterpret_cast<const void*>(expert_gemm),
                            hipFuncAttributeMaxDynamicSharedMemorySize, 131072);

  // 16 experts * 2 n-tiles * 32 m-tiles = 1024 blocks, 512 threads, 128 KiB LDS
  expert_gemm<<<1024, 512, 131072, stream>>>(xb, wb, b, out);
}